// Round 5
// baseline (139.482 us; speedup 1.0000x reference)
//
#include <hip/hip_runtime.h>

#define BB 64
#define KK 16
#define LL 16384
#define NROW (BB * KK)   // 1024 rows
#define SEGS 4           // blocks per row in K1/K2
#define CAP 512          // per-row candidate capacity

// monotone float->uint key so atomicMax(uint) orders like float
__device__ __forceinline__ unsigned fkey(float f) {
  unsigned u = __float_as_uint(f);
  return (u & 0x80000000u) ? ~u : (u | 0x80000000u);
}
__device__ __forceinline__ float funkey(unsigned k) {
  unsigned u = (k & 0x80000000u) ? (k & 0x7fffffffu) : ~k;
  return __uint_as_float(u);
}

// ---------------------------------------------------------------------------
// K1: blocks [0, NROW*SEGS): row-segment max -> atomicMax(rowmax[row]).
//     blocks [NROW*SEGS, +BB): per-batch mask stats (fused to save a launch).
// Shaped like fillBuffer: 4KB/block, tiny VGPR, no tails.
// ---------------------------------------------------------------------------
__global__ __launch_bounds__(256) void k1_rowmax_maskstats(
    const float* __restrict__ logits, const float* __restrict__ mask,
    unsigned* __restrict__ rowmax, float* __restrict__ stats) {
  int gb = blockIdx.x, t = threadIdx.x, wave = t >> 6, lane = t & 63;
  __shared__ float l0[4], l1[4];
  if (gb < NROW * SEGS) {
    int row = gb >> 2, seg = gb & 3;
    const float4* zv = reinterpret_cast<const float4*>(logits) +
                       (size_t)row * (LL / 4) + seg * (LL / 4 / SEGS);
    float4 a = zv[t], b4 = zv[t + 256], c = zv[t + 512], d = zv[t + 768];
    float m0 = fmaxf(fmaxf(a.x, a.y), fmaxf(a.z, a.w));
    float m1 = fmaxf(fmaxf(b4.x, b4.y), fmaxf(b4.z, b4.w));
    float m2 = fmaxf(fmaxf(c.x, c.y), fmaxf(c.z, c.w));
    float m3 = fmaxf(fmaxf(d.x, d.y), fmaxf(d.z, d.w));
    float m = fmaxf(fmaxf(m0, m1), fmaxf(m2, m3));
    for (int off = 32; off; off >>= 1) m = fmaxf(m, __shfl_xor(m, off));
    if (lane == 0) l0[wave] = m;
    __syncthreads();
    if (t == 0) {
      float bm = fmaxf(fmaxf(l0[0], l0[1]), fmaxf(l0[2], l0[3]));
      atomicMax(&rowmax[row], fkey(bm));
    }
  } else {
    int b = gb - NROW * SEGS;
    const float* m = mask + (size_t)b * LL;
    float s = 0.f, sq = 0.f;
#pragma unroll
    for (int j = 0; j < 16; ++j) {
      float4 v = reinterpret_cast<const float4*>(m)[j * 256 + t];
      s  += v.x + v.y + v.z + v.w;
      sq += v.x * v.x + v.y * v.y + v.z * v.z + v.w * v.w;
    }
    for (int off = 32; off; off >>= 1) {
      s += __shfl_xor(s, off); sq += __shfl_xor(sq, off);
    }
    if (lane == 0) { l0[wave] = s; l1[wave] = sq; }
    __syncthreads();
    if (t == 0) {
      float S  = l0[0] + l0[1] + l0[2] + l0[3];
      float SQ = l1[0] + l1[1] + l1[2] + l1[3];
      float inv = 1.0f / fmaxf(S, 1e-12f);
      stats[2 * b]     = inv;
      stats[2 * b + 1] = SQ * inv * inv;
    }
  }
}

// ---------------------------------------------------------------------------
// K2: re-read logits (L3-resident) and append candidates {z > rowmax-1}
//     into per-row global lists.  Candidates are a superset of the sparsemax
//     support (tau >= zmax-1 always).  ~40 appends per row.
// ---------------------------------------------------------------------------
__global__ __launch_bounds__(256) void k2_compact(
    const float* __restrict__ logits, const unsigned* __restrict__ rowmax,
    int* __restrict__ cnt, float* __restrict__ cval, int* __restrict__ cidx) {
  int gb = blockIdx.x;
  int row = gb >> 2, seg = gb & 3;
  int t = threadIdx.x;
  float thr = funkey(rowmax[row]) - 1.0f;
  const float4* zv = reinterpret_cast<const float4*>(logits) +
                     (size_t)row * (LL / 4) + seg * (LL / 4 / SEGS);
  float4 a = zv[t], b4 = zv[t + 256], c = zv[t + 512], d = zv[t + 768];
  int ebase = seg * (LL / SEGS);
  float vv[16] = {a.x,  a.y,  a.z,  a.w,  b4.x, b4.y, b4.z, b4.w,
                  c.x,  c.y,  c.z,  c.w,  d.x,  d.y,  d.z,  d.w};
  float* cv = cval + (size_t)row * CAP;
  int*   ci = cidx + (size_t)row * CAP;
#pragma unroll
  for (int j = 0; j < 16; ++j) {
    if (vv[j] > thr) {
      int idx = ebase + (j >> 2) * 1024 + t * 4 + (j & 3);
      int pos = atomicAdd(&cnt[row], 1);
      if (pos < CAP) { cv[pos] = vv[j]; ci[pos] = idx; }
    }
  }
}

// ---------------------------------------------------------------------------
// K3: one wave per row (4 independent waves/block, no inter-path barriers).
// Fast path (n<=64): bitonic sort + the reference's exact support test.
// Mid path (n<=CAP): bisection over the candidate list.
// Slow path (n>CAP, unreachable for N(0,1) data): full-row bisection.
// Loss = sum p^2 - 2 sum pq + sum q^2 (first two terms candidate-only).
// ---------------------------------------------------------------------------
__global__ __launch_bounds__(256) void k3_solve(
    const float* __restrict__ logits, const float* __restrict__ mask,
    const unsigned* __restrict__ rowmax, const int* __restrict__ cnt,
    const float* __restrict__ cval, const int* __restrict__ cidx,
    const float* __restrict__ stats, float* __restrict__ out) {
  int t = threadIdx.x, wave = t >> 6, lane = t & 63;
  int row = blockIdx.x * 4 + wave;
  int b = row >> 4;
  __shared__ float part[4];
  int n = cnt[row];
  float zmax = funkey(rowmax[row]);
  float thr = zmax - 1.0f;
  float inv_s = stats[2 * b], sumq2 = stats[2 * b + 1];
  const float scale = 0.5f / (float)(BB * KK);
  const float* m = mask + (size_t)b * LL;
  const float* cv = cval + (size_t)row * CAP;
  const int*   ci = cidx + (size_t)row * CAP;
  float a1 = 0.f, a2 = 0.f;

  if (n <= 64) {
    float c = (lane < n) ? cv[lane] : -3.0e38f;
    // bitonic sort, descending across 64 lanes
#pragma unroll
    for (int size = 2; size <= 64; size <<= 1) {
#pragma unroll
      for (int stride = size >> 1; stride > 0; stride >>= 1) {
        float other = __shfl_xor(c, stride);
        bool dirDesc = ((lane & size) == 0);
        bool takeMax = (dirDesc == ((lane & stride) == 0));
        c = takeMax ? fmaxf(c, other) : fminf(c, other);
      }
    }
    float cum = c;  // inclusive prefix sum
#pragma unroll
    for (int off = 1; off < 64; off <<= 1) {
      float y = __shfl_up(cum, off);
      if (lane >= off) cum += y;
    }
    bool sup = (lane < n) && (1.0f + (float)(lane + 1) * c > cum);
    unsigned long long bal = __ballot(sup);
    int k = __popcll(bal);              // k >= 1 (max element always in)
    float S = sup ? c : 0.f;
    for (int off = 32; off; off >>= 1) S += __shfl_xor(S, off);
    float tau = (S - 1.0f) / (float)k;
    if (lane < n) {
      float val = cv[lane];
      float p = fmaxf(val - tau, 0.f);
      if (p > 0.f) { float q = m[ci[lane]] * inv_s; a1 = p * p; a2 = p * q; }
    }
  } else if (n <= CAP) {
    int nj = (n + 63) >> 6;
    float lo = thr, hi = zmax;
    for (int it = 0; it < 30; ++it) {
      float mid = 0.5f * (lo + hi), s = 0.f;
      for (int j = 0; j < nj; ++j) {
        int i = j * 64 + lane;
        float cc = (i < n) ? cv[i] : -3.0e38f;
        s += fmaxf(cc - mid, 0.f);
      }
      for (int off = 32; off; off >>= 1) s += __shfl_xor(s, off);
      if (s >= 1.0f) lo = mid; else hi = mid;
    }
    float S = 0.f, kc = 0.f;
    for (int j = 0; j < nj; ++j) {
      int i = j * 64 + lane;
      float cc = (i < n) ? cv[i] : -3.0e38f;
      if (cc > lo) { S += cc; kc += 1.f; }
    }
    for (int off = 32; off; off >>= 1) {
      S += __shfl_xor(S, off); kc += __shfl_xor(kc, off);
    }
    float tau = (S - 1.0f) / kc;
    for (int j = 0; j < nj; ++j) {
      int i = j * 64 + lane;
      if (i < n) {
        float p = fmaxf(cv[i] - tau, 0.f);
        if (p > 0.f) { float q = m[ci[i]] * inv_s; a1 += p * p; a2 += p * q; }
      }
    }
  } else {
    // full-row fallback, correctness only
    const float* z = logits + (size_t)row * LL;
    float lo = thr, hi = zmax;
    for (int it = 0; it < 30; ++it) {
      float mid = 0.5f * (lo + hi), s = 0.f;
      for (int i = lane; i < LL; i += 64) s += fmaxf(z[i] - mid, 0.f);
      for (int off = 32; off; off >>= 1) s += __shfl_xor(s, off);
      if (s >= 1.0f) lo = mid; else hi = mid;
    }
    float S = 0.f, kc = 0.f;
    for (int i = lane; i < LL; i += 64) {
      float zi = z[i];
      if (zi > lo) { S += zi; kc += 1.f; }
    }
    for (int off = 32; off; off >>= 1) {
      S += __shfl_xor(S, off); kc += __shfl_xor(kc, off);
    }
    float tau = (S - 1.0f) / kc;
    for (int i = lane; i < LL; i += 64) {
      float p = fmaxf(z[i] - tau, 0.f);
      if (p > 0.f) { float q = m[i] * inv_s; a1 += p * p; a2 += p * q; }
    }
  }

  for (int off = 32; off; off >>= 1) {
    a1 += __shfl_xor(a1, off); a2 += __shfl_xor(a2, off);
  }
  if (lane == 0) part[wave] = (a1 - 2.f * a2 + sumq2) * scale;
  __syncthreads();
  if (t == 0) atomicAdd(out, part[0] + part[1] + part[2] + part[3]);
}

extern "C" void kernel_launch(void* const* d_in, const int* in_sizes, int n_in,
                              void* d_out, int out_size, void* d_ws, size_t ws_size,
                              hipStream_t stream) {
  const float* logits = (const float*)d_in[0];  // (B,K,L) fp32
  const float* mask   = (const float*)d_in[1];  // (B,L)   fp32
  char* ws = (char*)d_ws;
  // ws layout: [0,512) stats | [512,4608) rowmax | [4608,8704) cnt |
  //            [16384, +2MB) cval | then cidx (+2MB)
  float*    stats  = (float*)ws;
  unsigned* rowmax = (unsigned*)(ws + 512);
  int*      cnt    = (int*)(ws + 512 + 4096);
  float*    cval   = (float*)(ws + 16384);
  int*      cidx   = (int*)(ws + 16384 + (size_t)NROW * CAP * 4);
  float* out = (float*)d_out;

  hipMemsetAsync(out, 0, sizeof(float), stream);
  hipMemsetAsync(ws + 512, 0, 8192, stream);  // rowmax keys (=-inf) + cnt
  k1_rowmax_maskstats<<<NROW * SEGS + BB, 256, 0, stream>>>(logits, mask, rowmax, stats);
  k2_compact<<<NROW * SEGS, 256, 0, stream>>>(logits, rowmax, cnt, cval, cidx);
  k3_solve<<<NROW / 4, 256, 0, stream>>>(logits, mask, rowmax, cnt, cval, cidx, stats, out);
}

// Round 6
// 117.434 us; speedup vs baseline: 1.1877x; 1.1877x over previous
//
#include <hip/hip_runtime.h>

#define BB 64
#define KK 16
#define LL 16384
#define NROW (BB * KK)
#define NCHUNK 60          // 60 chunks x 256 floats staged to LDS = 61440 B
#define CHUNKS_PER_WAVE 15 // 60 / 4 waves
#define LDSF (NCHUNK * 256)   // 15360 floats in LDS
#define TAILB LDSF            // elements [15360, 16384) live in registers
#define CAPL 256              // LDS candidate capacity

#define AS1 __attribute__((address_space(1)))
#define AS3 __attribute__((address_space(3)))

// async global->LDS DMA, 16 B/lane, no VGPR round-trip.  Lane i's data lands
// at lds_base + i*16 (wave-uniform base), which matches our contiguous layout.
__device__ __forceinline__ void async_load16(const float* g, float* l) {
  __builtin_amdgcn_global_load_lds((const AS1 unsigned int*)g,
                                   (AS3 unsigned int*)l, 16, 0, 0);
}

// ---------------------------------------------------------------------------
// K1: per-batch mask statistics.
//   stats[2b] = 1/max(sum(mask),1e-12); stats[2b+1] = sum q^2
// ---------------------------------------------------------------------------
__global__ __launch_bounds__(256) void mask_stats_kernel(
    const float* __restrict__ mask, float* __restrict__ stats) {
  int b = blockIdx.x;
  const float* m = mask + (size_t)b * LL;
  int t = threadIdx.x;
  float s = 0.f, sq = 0.f;
#pragma unroll
  for (int j = 0; j < 16; ++j) {
    float4 v = reinterpret_cast<const float4*>(m)[j * 256 + t];
    s  += v.x + v.y + v.z + v.w;
    sq += v.x * v.x + v.y * v.y + v.z * v.z + v.w * v.w;
  }
  for (int off = 32; off; off >>= 1) {
    s += __shfl_xor(s, off); sq += __shfl_xor(sq, off);
  }
  __shared__ float ls[4], lsq[4];
  int wave = t >> 6;
  if ((t & 63) == 0) { ls[wave] = s; lsq[wave] = sq; }
  __syncthreads();
  if (t == 0) {
    float S  = ls[0] + ls[1] + ls[2] + ls[3];
    float SQ = lsq[0] + lsq[1] + lsq[2] + lsq[3];
    float inv = 1.0f / fmaxf(S, 1e-12f);
    stats[2 * b]     = inv;
    stats[2 * b + 1] = SQ * inv * inv;
  }
}

// ---------------------------------------------------------------------------
// K2: one block per row.  The row is staged ONCE into LDS via async
// global_load_lds (15 outstanding DMAs per wave, zero VGPR results -> the
// compiler cannot batch-serialize the loads, unlike R2-R5 where every
// structure collapsed to ~1.7 TB/s).  Elements [15360,16384) ride in one
// float4/thread.  Max + candidate compaction then read LDS at ~69 TB/s.
// Candidates {z > zmax-1} are a superset of the support (tau >= zmax-1).
// Fast path: wave 0 bitonic-sorts <=64 candidates and applies the
// reference's exact support test.  Loss = sum p^2 - 2 sum pq + sum q^2.
// ---------------------------------------------------------------------------
__global__ __launch_bounds__(256, 2) void sparsemax_loss_kernel(
    const float* __restrict__ logits, const float* __restrict__ mask,
    const float* __restrict__ stats, float* __restrict__ out) {
  int row = blockIdx.x;
  int b = row >> 4;            // K == 16
  const float* z = logits + (size_t)row * LL;
  const float* m = mask + (size_t)b * LL;
  int t = threadIdx.x, wave = t >> 6, lane = t & 63;

  __shared__ float zrow[LDSF];        // 61440 B
  __shared__ float cand_v[CAPL];      // 1024 B
  __shared__ int   cand_i[CAPL];      // 1024 B
  __shared__ float lds_f[4], red0[4], red1[4];
  __shared__ int   lds_n;

  if (t == 0) lds_n = 0;

  // ---- stage: 15 async DMAs per wave, all in flight at once ----
#pragma unroll
  for (int j = 0; j < CHUNKS_PER_WAVE; ++j) {
    int c = wave * CHUNKS_PER_WAVE + j;
    async_load16(z + c * 256 + lane * 4, &zrow[c * 256]);
  }
  float4 tail = reinterpret_cast<const float4*>(z)[TAILB / 4 + t];
  __syncthreads();   // drains vmcnt (DMAs + tail) before LDS reads

  // ---- max over LDS row + register tail ----
  const float4* zl = reinterpret_cast<const float4*>(zrow);
  float mx = fmaxf(fmaxf(tail.x, tail.y), fmaxf(tail.z, tail.w));
#pragma unroll
  for (int j = 0; j < 15; ++j) {
    float4 a = zl[j * 256 + t];
    mx = fmaxf(mx, fmaxf(fmaxf(a.x, a.y), fmaxf(a.z, a.w)));
  }
  for (int off = 32; off; off >>= 1) mx = fmaxf(mx, __shfl_xor(mx, off));
  if (lane == 0) lds_f[wave] = mx;
  __syncthreads();
  float zmax = fmaxf(fmaxf(lds_f[0], lds_f[1]), fmaxf(lds_f[2], lds_f[3]));
  float thr = zmax - 1.0f;

  // ---- compact candidates (LDS row + register tail) into LDS lists ----
#pragma unroll
  for (int j = 0; j < 15; ++j) {
    float4 a = zl[j * 256 + t];
    int base = (j * 256 + t) * 4;
    float vv[4] = {a.x, a.y, a.z, a.w};
#pragma unroll
    for (int e = 0; e < 4; ++e) {
      if (vv[e] > thr) {
        int pos = atomicAdd(&lds_n, 1);
        if (pos < CAPL) { cand_v[pos] = vv[e]; cand_i[pos] = base + e; }
      }
    }
  }
  {
    int base = TAILB + t * 4;
    float vv[4] = {tail.x, tail.y, tail.z, tail.w};
#pragma unroll
    for (int e = 0; e < 4; ++e) {
      if (vv[e] > thr) {
        int pos = atomicAdd(&lds_n, 1);
        if (pos < CAPL) { cand_v[pos] = vv[e]; cand_i[pos] = base + e; }
      }
    }
  }
  __syncthreads();
  int n = lds_n;
  float inv_s = stats[2 * b], sumq2 = stats[2 * b + 1];
  const float scale = 0.5f / (float)(BB * KK);

  if (n <= 64) {
    // ---------- fast path: exact sorted solve on wave 0 ----------
    if (wave == 0) {
      float c = (lane < n) ? cand_v[lane] : -3.0e38f;
#pragma unroll
      for (int size = 2; size <= 64; size <<= 1) {
#pragma unroll
        for (int stride = size >> 1; stride > 0; stride >>= 1) {
          float other = __shfl_xor(c, stride);
          bool dirDesc = ((lane & size) == 0);
          bool takeMax = (dirDesc == ((lane & stride) == 0));
          c = takeMax ? fmaxf(c, other) : fminf(c, other);
        }
      }
      float cum = c;
#pragma unroll
      for (int off = 1; off < 64; off <<= 1) {
        float y = __shfl_up(cum, off);
        if (lane >= off) cum += y;
      }
      bool sup = (lane < n) && (1.0f + (float)(lane + 1) * c > cum);
      unsigned long long bal = __ballot(sup);
      int k = __popcll(bal);
      float S = sup ? c : 0.f;
      for (int off = 32; off; off >>= 1) S += __shfl_xor(S, off);
      float tau = (S - 1.0f) / (float)k;

      float a1 = 0.f, a2 = 0.f;
      if (lane < n) {
        float val = cand_v[lane];
        float p = fmaxf(val - tau, 0.f);
        if (p > 0.f) { float q = m[cand_i[lane]] * inv_s; a1 = p * p; a2 = p * q; }
      }
      for (int off = 32; off; off >>= 1) {
        a1 += __shfl_xor(a1, off); a2 += __shfl_xor(a2, off);
      }
      if (lane == 0) atomicAdd(out, (a1 - 2.f * a2 + sumq2) * scale);
    }
  } else if (n <= CAPL) {
    // ---------- mid path: wave-0 bisection over LDS candidates ----------
    if (wave == 0) {
      int nj = (n + 63) >> 6;
      float lo = thr, hi = zmax;
      for (int it = 0; it < 30; ++it) {
        float mid = 0.5f * (lo + hi), s = 0.f;
        for (int j = 0; j < nj; ++j) {
          int i = j * 64 + lane;
          float cc = (i < n) ? cand_v[i] : -3.0e38f;
          s += fmaxf(cc - mid, 0.f);
        }
        for (int off = 32; off; off >>= 1) s += __shfl_xor(s, off);
        if (s >= 1.0f) lo = mid; else hi = mid;
      }
      float S = 0.f, kc = 0.f;
      for (int j = 0; j < nj; ++j) {
        int i = j * 64 + lane;
        float cc = (i < n) ? cand_v[i] : -3.0e38f;
        if (cc > lo) { S += cc; kc += 1.f; }
      }
      for (int off = 32; off; off >>= 1) {
        S += __shfl_xor(S, off); kc += __shfl_xor(kc, off);
      }
      float tau = (S - 1.0f) / kc;
      float a1 = 0.f, a2 = 0.f;
      for (int j = 0; j < nj; ++j) {
        int i = j * 64 + lane;
        if (i < n) {
          float p = fmaxf(cand_v[i] - tau, 0.f);
          if (p > 0.f) { float q = m[cand_i[i]] * inv_s; a1 += p * p; a2 += p * q; }
        }
      }
      for (int off = 32; off; off >>= 1) {
        a1 += __shfl_xor(a1, off); a2 += __shfl_xor(a2, off);
      }
      if (lane == 0) atomicAdd(out, (a1 - 2.f * a2 + sumq2) * scale);
    }
  } else {
    // ---------- slow path (unreachable for N(0,1)): block bisection over
    //            the on-chip row (LDS + register tail); correctness only ---
    float lo = thr, hi = zmax;
    for (int it = 0; it < 30; ++it) {
      float mid = 0.5f * (lo + hi);
      float s = fmaxf(tail.x - mid, 0.f) + fmaxf(tail.y - mid, 0.f) +
                fmaxf(tail.z - mid, 0.f) + fmaxf(tail.w - mid, 0.f);
      for (int j = 0; j < 15; ++j) {
        float4 a = zl[j * 256 + t];
        s += fmaxf(a.x - mid, 0.f) + fmaxf(a.y - mid, 0.f) +
             fmaxf(a.z - mid, 0.f) + fmaxf(a.w - mid, 0.f);
      }
      for (int off = 32; off; off >>= 1) s += __shfl_xor(s, off);
      __syncthreads();
      if (lane == 0) red0[wave] = s;
      __syncthreads();
      float tot = red0[0] + red0[1] + red0[2] + red0[3];
      if (tot >= 1.0f) lo = mid; else hi = mid;
    }
    float S = 0.f, kc = 0.f;
    {
      float vv[4] = {tail.x, tail.y, tail.z, tail.w};
      for (int e = 0; e < 4; ++e) if (vv[e] > lo) { S += vv[e]; kc += 1.f; }
    }
    for (int j = 0; j < 15; ++j) {
      float4 a = zl[j * 256 + t];
      float vv[4] = {a.x, a.y, a.z, a.w};
      for (int e = 0; e < 4; ++e) if (vv[e] > lo) { S += vv[e]; kc += 1.f; }
    }
    for (int off = 32; off; off >>= 1) {
      S += __shfl_xor(S, off); kc += __shfl_xor(kc, off);
    }
    __syncthreads();
    if (lane == 0) { red0[wave] = S; red1[wave] = kc; }
    __syncthreads();
    S  = red0[0] + red0[1] + red0[2] + red0[3];
    kc = red1[0] + red1[1] + red1[2] + red1[3];
    float tau = (S - 1.0f) / kc;

    float a1 = 0.f, a2 = 0.f;
    for (int j = 0; j < 15; ++j) {
      float4 a = zl[j * 256 + t];
      int base = (j * 256 + t) * 4;
      float vv[4] = {a.x, a.y, a.z, a.w};
      for (int e = 0; e < 4; ++e) {
        float p = fmaxf(vv[e] - tau, 0.f);
        if (p > 0.f) { float q = m[base + e] * inv_s; a1 += p * p; a2 += p * q; }
      }
    }
    {
      int base = TAILB + t * 4;
      float vv[4] = {tail.x, tail.y, tail.z, tail.w};
      for (int e = 0; e < 4; ++e) {
        float p = fmaxf(vv[e] - tau, 0.f);
        if (p > 0.f) { float q = m[base + e] * inv_s; a1 += p * p; a2 += p * q; }
      }
    }
    for (int off = 32; off; off >>= 1) {
      a1 += __shfl_xor(a1, off); a2 += __shfl_xor(a2, off);
    }
    __syncthreads();
    if (lane == 0) { red0[wave] = a1; red1[wave] = a2; }
    __syncthreads();
    if (t == 0) {
      a1 = red0[0] + red0[1] + red0[2] + red0[3];
      a2 = red1[0] + red1[1] + red1[2] + red1[3];
      atomicAdd(out, (a1 - 2.f * a2 + sumq2) * scale);
    }
  }
}

extern "C" void kernel_launch(void* const* d_in, const int* in_sizes, int n_in,
                              void* d_out, int out_size, void* d_ws, size_t ws_size,
                              hipStream_t stream) {
  const float* logits = (const float*)d_in[0];  // (B,K,L) fp32
  const float* mask   = (const float*)d_in[1];  // (B,L)   fp32
  float* stats = (float*)d_ws;                  // 64*2 floats
  float* out   = (float*)d_out;

  hipMemsetAsync(out, 0, sizeof(float), stream);
  mask_stats_kernel<<<BB, 256, 0, stream>>>(mask, stats);
  sparsemax_loss_kernel<<<NROW, 256, 0, stream>>>(logits, mask, stats, out);
}

// Round 7
// 115.927 us; speedup vs baseline: 1.2032x; 1.0130x over previous
//
#include <hip/hip_runtime.h>

#define BB 64
#define KK 16
#define LL 16384
#define NROW (BB * KK)
#define NCHUNK 60          // 60 chunks x 256 floats staged to LDS = 61440 B
#define CHUNKS_PER_WAVE 15 // 60 / 4 waves
#define LDSF (NCHUNK * 256)   // 15360 floats in LDS
#define TAILB LDSF            // elements [15360, 16384) live in registers
#define CAPL 256              // LDS candidate capacity

#define AS1 __attribute__((address_space(1)))
#define AS3 __attribute__((address_space(3)))

// async global->LDS DMA, 16 B/lane, no VGPR round-trip.
__device__ __forceinline__ void async_load16(const float* g, float* l) {
  __builtin_amdgcn_global_load_lds((const AS1 unsigned int*)g,
                                   (AS3 unsigned int*)l, 16, 0, 0);
}

// ---------------------------------------------------------------------------
// K1: per-batch mask statistics.
// ---------------------------------------------------------------------------
__global__ __launch_bounds__(256) void mask_stats_kernel(
    const float* __restrict__ mask, float* __restrict__ stats) {
  int b = blockIdx.x;
  const float* m = mask + (size_t)b * LL;
  int t = threadIdx.x;
  float s = 0.f, sq = 0.f;
#pragma unroll
  for (int j = 0; j < 16; ++j) {
    float4 v = reinterpret_cast<const float4*>(m)[j * 256 + t];
    s  += v.x + v.y + v.z + v.w;
    sq += v.x * v.x + v.y * v.y + v.z * v.z + v.w * v.w;
  }
  for (int off = 32; off; off >>= 1) {
    s += __shfl_xor(s, off); sq += __shfl_xor(sq, off);
  }
  __shared__ float ls[4], lsq[4];
  int wave = t >> 6;
  if ((t & 63) == 0) { ls[wave] = s; lsq[wave] = sq; }
  __syncthreads();
  if (t == 0) {
    float S  = ls[0] + ls[1] + ls[2] + ls[3];
    float SQ = lsq[0] + lsq[1] + lsq[2] + lsq[3];
    float inv = 1.0f / fmaxf(S, 1e-12f);
    stats[2 * b]     = inv;
    stats[2 * b + 1] = SQ * inv * inv;
  }
}

// ---------------------------------------------------------------------------
// K2: one block per row (identical to R6 EXCEPT: per-row loss goes to
// part[row] via a plain store instead of atomicAdd(out) — isolating the
// 1024-same-address-atomic drain hypothesis).
// ---------------------------------------------------------------------------
__global__ __launch_bounds__(256, 2) void sparsemax_loss_kernel(
    const float* __restrict__ logits, const float* __restrict__ mask,
    const float* __restrict__ stats, float* __restrict__ part) {
  int row = blockIdx.x;
  int b = row >> 4;            // K == 16
  const float* z = logits + (size_t)row * LL;
  const float* m = mask + (size_t)b * LL;
  int t = threadIdx.x, wave = t >> 6, lane = t & 63;

  __shared__ float zrow[LDSF];
  __shared__ float cand_v[CAPL];
  __shared__ int   cand_i[CAPL];
  __shared__ float lds_f[4], red0[4], red1[4];
  __shared__ int   lds_n;

  if (t == 0) lds_n = 0;

  // ---- stage: 15 async DMAs per wave ----
#pragma unroll
  for (int j = 0; j < CHUNKS_PER_WAVE; ++j) {
    int c = wave * CHUNKS_PER_WAVE + j;
    async_load16(z + c * 256 + lane * 4, &zrow[c * 256]);
  }
  float4 tail = reinterpret_cast<const float4*>(z)[TAILB / 4 + t];
  __syncthreads();

  // ---- max over LDS row + register tail ----
  const float4* zl = reinterpret_cast<const float4*>(zrow);
  float mx = fmaxf(fmaxf(tail.x, tail.y), fmaxf(tail.z, tail.w));
#pragma unroll
  for (int j = 0; j < 15; ++j) {
    float4 a = zl[j * 256 + t];
    mx = fmaxf(mx, fmaxf(fmaxf(a.x, a.y), fmaxf(a.z, a.w)));
  }
  for (int off = 32; off; off >>= 1) mx = fmaxf(mx, __shfl_xor(mx, off));
  if (lane == 0) lds_f[wave] = mx;
  __syncthreads();
  float zmax = fmaxf(fmaxf(lds_f[0], lds_f[1]), fmaxf(lds_f[2], lds_f[3]));
  float thr = zmax - 1.0f;

  // ---- compact candidates into LDS lists ----
#pragma unroll
  for (int j = 0; j < 15; ++j) {
    float4 a = zl[j * 256 + t];
    int base = (j * 256 + t) * 4;
    float vv[4] = {a.x, a.y, a.z, a.w};
#pragma unroll
    for (int e = 0; e < 4; ++e) {
      if (vv[e] > thr) {
        int pos = atomicAdd(&lds_n, 1);
        if (pos < CAPL) { cand_v[pos] = vv[e]; cand_i[pos] = base + e; }
      }
    }
  }
  {
    int base = TAILB + t * 4;
    float vv[4] = {tail.x, tail.y, tail.z, tail.w};
#pragma unroll
    for (int e = 0; e < 4; ++e) {
      if (vv[e] > thr) {
        int pos = atomicAdd(&lds_n, 1);
        if (pos < CAPL) { cand_v[pos] = vv[e]; cand_i[pos] = base + e; }
      }
    }
  }
  __syncthreads();
  int n = lds_n;
  float inv_s = stats[2 * b], sumq2 = stats[2 * b + 1];
  const float scale = 0.5f / (float)(BB * KK);

  if (n <= 64) {
    // ---------- fast path: exact sorted solve on wave 0 ----------
    if (wave == 0) {
      float c = (lane < n) ? cand_v[lane] : -3.0e38f;
#pragma unroll
      for (int size = 2; size <= 64; size <<= 1) {
#pragma unroll
        for (int stride = size >> 1; stride > 0; stride >>= 1) {
          float other = __shfl_xor(c, stride);
          bool dirDesc = ((lane & size) == 0);
          bool takeMax = (dirDesc == ((lane & stride) == 0));
          c = takeMax ? fmaxf(c, other) : fminf(c, other);
        }
      }
      float cum = c;
#pragma unroll
      for (int off = 1; off < 64; off <<= 1) {
        float y = __shfl_up(cum, off);
        if (lane >= off) cum += y;
      }
      bool sup = (lane < n) && (1.0f + (float)(lane + 1) * c > cum);
      unsigned long long bal = __ballot(sup);
      int k = __popcll(bal);
      float S = sup ? c : 0.f;
      for (int off = 32; off; off >>= 1) S += __shfl_xor(S, off);
      float tau = (S - 1.0f) / (float)k;

      float a1 = 0.f, a2 = 0.f;
      if (lane < n) {
        float val = cand_v[lane];
        float p = fmaxf(val - tau, 0.f);
        if (p > 0.f) { float q = m[cand_i[lane]] * inv_s; a1 = p * p; a2 = p * q; }
      }
      for (int off = 32; off; off >>= 1) {
        a1 += __shfl_xor(a1, off); a2 += __shfl_xor(a2, off);
      }
      if (lane == 0) part[row] = (a1 - 2.f * a2 + sumq2) * scale;
    }
  } else if (n <= CAPL) {
    // ---------- mid path: wave-0 bisection over LDS candidates ----------
    if (wave == 0) {
      int nj = (n + 63) >> 6;
      float lo = thr, hi = zmax;
      for (int it = 0; it < 30; ++it) {
        float mid = 0.5f * (lo + hi), s = 0.f;
        for (int j = 0; j < nj; ++j) {
          int i = j * 64 + lane;
          float cc = (i < n) ? cand_v[i] : -3.0e38f;
          s += fmaxf(cc - mid, 0.f);
        }
        for (int off = 32; off; off >>= 1) s += __shfl_xor(s, off);
        if (s >= 1.0f) lo = mid; else hi = mid;
      }
      float S = 0.f, kc = 0.f;
      for (int j = 0; j < nj; ++j) {
        int i = j * 64 + lane;
        float cc = (i < n) ? cand_v[i] : -3.0e38f;
        if (cc > lo) { S += cc; kc += 1.f; }
      }
      for (int off = 32; off; off >>= 1) {
        S += __shfl_xor(S, off); kc += __shfl_xor(kc, off);
      }
      float tau = (S - 1.0f) / kc;
      float a1 = 0.f, a2 = 0.f;
      for (int j = 0; j < nj; ++j) {
        int i = j * 64 + lane;
        if (i < n) {
          float p = fmaxf(cand_v[i] - tau, 0.f);
          if (p > 0.f) { float q = m[cand_i[i]] * inv_s; a1 += p * p; a2 += p * q; }
        }
      }
      for (int off = 32; off; off >>= 1) {
        a1 += __shfl_xor(a1, off); a2 += __shfl_xor(a2, off);
      }
      if (lane == 0) part[row] = (a1 - 2.f * a2 + sumq2) * scale;
    }
  } else {
    // ---------- slow path (unreachable for N(0,1)); correctness only -----
    float lo = thr, hi = zmax;
    for (int it = 0; it < 30; ++it) {
      float mid = 0.5f * (lo + hi);
      float s = fmaxf(tail.x - mid, 0.f) + fmaxf(tail.y - mid, 0.f) +
                fmaxf(tail.z - mid, 0.f) + fmaxf(tail.w - mid, 0.f);
      for (int j = 0; j < 15; ++j) {
        float4 a = zl[j * 256 + t];
        s += fmaxf(a.x - mid, 0.f) + fmaxf(a.y - mid, 0.f) +
             fmaxf(a.z - mid, 0.f) + fmaxf(a.w - mid, 0.f);
      }
      for (int off = 32; off; off >>= 1) s += __shfl_xor(s, off);
      __syncthreads();
      if (lane == 0) red0[wave] = s;
      __syncthreads();
      float tot = red0[0] + red0[1] + red0[2] + red0[3];
      if (tot >= 1.0f) lo = mid; else hi = mid;
    }
    float S = 0.f, kc = 0.f;
    {
      float vv[4] = {tail.x, tail.y, tail.z, tail.w};
      for (int e = 0; e < 4; ++e) if (vv[e] > lo) { S += vv[e]; kc += 1.f; }
    }
    for (int j = 0; j < 15; ++j) {
      float4 a = zl[j * 256 + t];
      float vv[4] = {a.x, a.y, a.z, a.w};
      for (int e = 0; e < 4; ++e) if (vv[e] > lo) { S += vv[e]; kc += 1.f; }
    }
    for (int off = 32; off; off >>= 1) {
      S += __shfl_xor(S, off); kc += __shfl_xor(kc, off);
    }
    __syncthreads();
    if (lane == 0) { red0[wave] = S; red1[wave] = kc; }
    __syncthreads();
    S  = red0[0] + red0[1] + red0[2] + red0[3];
    kc = red1[0] + red1[1] + red1[2] + red1[3];
    float tau = (S - 1.0f) / kc;

    float a1 = 0.f, a2 = 0.f;
    for (int j = 0; j < 15; ++j) {
      float4 a = zl[j * 256 + t];
      int base = (j * 256 + t) * 4;
      float vv[4] = {a.x, a.y, a.z, a.w};
      for (int e = 0; e < 4; ++e) {
        float p = fmaxf(vv[e] - tau, 0.f);
        if (p > 0.f) { float q = m[base + e] * inv_s; a1 += p * p; a2 += p * q; }
      }
    }
    {
      int base = TAILB + t * 4;
      float vv[4] = {tail.x, tail.y, tail.z, tail.w};
      for (int e = 0; e < 4; ++e) {
        float p = fmaxf(vv[e] - tau, 0.f);
        if (p > 0.f) { float q = m[base + e] * inv_s; a1 += p * p; a2 += p * q; }
      }
    }
    for (int off = 32; off; off >>= 1) {
      a1 += __shfl_xor(a1, off); a2 += __shfl_xor(a2, off);
    }
    __syncthreads();
    if (lane == 0) { red0[wave] = a1; red1[wave] = a2; }
    __syncthreads();
    if (t == 0) {
      a1 = red0[0] + red0[1] + red0[2] + red0[3];
      a2 = red1[0] + red1[1] + red1[2] + red1[3];
      part[row] = (a1 - 2.f * a2 + sumq2) * scale;
    }
  }
}

// ---------------------------------------------------------------------------
// K3: single-block final reduction of the 1024 per-row losses.
// ---------------------------------------------------------------------------
__global__ __launch_bounds__(256) void k3_reduce(
    const float* __restrict__ part, float* __restrict__ out) {
  int t = threadIdx.x;
  float s = 0.f;
#pragma unroll
  for (int j = 0; j < NROW / 256; ++j) s += part[j * 256 + t];
  for (int off = 32; off; off >>= 1) s += __shfl_xor(s, off);
  __shared__ float ls[4];
  if ((t & 63) == 0) ls[t >> 6] = s;
  __syncthreads();
  if (t == 0) out[0] = ls[0] + ls[1] + ls[2] + ls[3];
}

extern "C" void kernel_launch(void* const* d_in, const int* in_sizes, int n_in,
                              void* d_out, int out_size, void* d_ws, size_t ws_size,
                              hipStream_t stream) {
  const float* logits = (const float*)d_in[0];  // (B,K,L) fp32
  const float* mask   = (const float*)d_in[1];  // (B,L)   fp32
  float* stats = (float*)d_ws;                  // [0, 512):   64*2 floats
  float* part  = (float*)((char*)d_ws + 1024);  // [1024, +4KB): 1024 floats
  float* out   = (float*)d_out;

  mask_stats_kernel<<<BB, 256, 0, stream>>>(mask, stats);
  sparsemax_loss_kernel<<<NROW, 256, 0, stream>>>(logits, mask, stats, part);
  k3_reduce<<<1, 256, 0, stream>>>(part, out);
}